// Round 3
// baseline (75.936 us; speedup 1.0000x reference)
//
#include <hip/hip_runtime.h>
#include <math.h>
#include <stdint.h>

#define HIDDEN 128
#define D_IN 28
#define T_STEPS 28

// One block = one batch, 512 threads (8 waves). Thread t = (row = t>>2,
// q = t&3). q selects BOTH a 32-wide W_res k-slice [32q,32q+32) and an
// 8-wide W_in col-slice [8q,8q+8) (q==3 tail zero-padded); partials are
// combined by one quad __shfl_xor reduce.
// R5 post-mortem: R0 and R5 have IDENTICAL per-step LDS instruction totals
// (~64 b128 h + ~28-56 x per CU) and identical times -> the bottleneck is
// DS-pipe throughput (64 KB/step of redundant h broadcast), not latency or
// barrier. R6 stores h and staged x in LDS as bf16: h = 4 b128/lane (was 8),
// x = 1 b128/lane (was 7 scalar b32) -> ~40 b128/step/CU, -60% DS cycles.
// bf16 unpack is one VALU shift per value (f32 high half), hidden under DS.
// Final step's h kept f32 for the output head; all weights stay f32.
// BURN=0: contraction <=0.78/step; bf16-h steady-state noise ~4e-3 ->
// predicted absmax ~0.02 vs 4.25e-2 threshold.
__global__ __launch_bounds__(512, 1)
void esn_kernel(const float* __restrict__ x,      // (256,28,28)
                const float* __restrict__ W_in,   // (128,28)
                const float* __restrict__ W_res,  // (128,128)
                const float* __restrict__ W_out,  // (10,128)
                const float* __restrict__ b_out,  // (10,)
                float* __restrict__ out)          // (256,10)
{
    __shared__ alignas(16) unsigned short xs16[T_STEPS][32];  // bf16 x, rows padded to 32
    __shared__ alignas(16) unsigned short hs16[2][HIDDEN];    // bf16 h, double-buffered
    __shared__ alignas(16) float hf32[HIDDEN];                // final-step h (f32) for head

    const int b = blockIdx.x;
    const int t = threadIdx.x;        // 0..511
    const int row = t >> 2;           // 0..127
    const int q   = t & 3;

    // ---- stage x as bf16 (RNE: +0x7FFF + lsb) ----
    const float* xb = x + b * (T_STEPS * D_IN);
    for (int i = t; i < T_STEPS * D_IN; i += 512) {
        union { float f; uint32_t u; } cv; cv.f = xb[i];
        const uint32_t r = cv.u + 0x7FFFu + ((cv.u >> 16) & 1u);
        xs16[i / D_IN][i % D_IN] = (unsigned short)(r >> 16);
    }
    if (t < T_STEPS * 4) xs16[t >> 2][28 + (t & 3)] = 0;   // zero the pad cols
    if (t < HIDDEN) hs16[0][t] = 0;                        // h0 = 0 (bf16 zero)

    // ---- W_res k-slice [32q, 32q+32) in named f32 registers ----
    const float4* wr = (const float4*)(W_res + row * HIDDEN + 32 * q);
    const float4 W0 = wr[0], W1 = wr[1], W2 = wr[2], W3 = wr[3];
    const float4 W4 = wr[4], W5 = wr[5], W6 = wr[6], W7 = wr[7];

    // ---- W_in col-slice [8q, 8q+8); q==3 upper half zeroed (pairs with
    // zeroed xs16 pad cols; avoids OOB read past W_in end on row 127) ----
    const float4* wi4 = (const float4*)(W_in + row * D_IN + 8 * q);
    const float4 I0 = wi4[0];
    float4 I1 = make_float4(0.f, 0.f, 0.f, 0.f);
    if (q != 3) I1 = wi4[1];

    __syncthreads();

    // bf16 unpack: value sits in the high half of a f32
#define BFLO(w) __uint_as_float((uint32_t)(w) << 16)
#define BFHI(w) __uint_as_float((uint32_t)(w) & 0xFFFF0000u)

    // 8-wide x-projection slice: ONE b128 broadcast read
#define XDOT(dst, sidx) {                                                     \
        const uint4 xu = *(const uint4*)(&xs16[sidx][8 * q]);                 \
        float b0 = I0.x * BFLO(xu.x), b1 = I0.y * BFHI(xu.x);                 \
        float b2 = I0.z * BFLO(xu.y), b3 = I0.w * BFHI(xu.y);                 \
        b0 = fmaf(I1.x, BFLO(xu.z), b0); b1 = fmaf(I1.y, BFHI(xu.z), b1);     \
        b2 = fmaf(I1.z, BFLO(xu.w), b2); b3 = fmaf(I1.w, BFHI(xu.w), b3);     \
        dst = (b0 + b1) + (b2 + b3); }

    // 8 recurrent MACs from one uint4 (8 bf16 h values)
#define HFMA8(u, Wa, Wb) {                                                    \
        a0 = fmaf(Wa.x, BFLO(u.x), a0); a1 = fmaf(Wa.y, BFHI(u.x), a1);       \
        a2 = fmaf(Wa.z, BFLO(u.y), a2); a3 = fmaf(Wa.w, BFHI(u.y), a3);       \
        a0 = fmaf(Wb.x, BFLO(u.z), a0); a1 = fmaf(Wb.y, BFHI(u.z), a1);       \
        a2 = fmaf(Wb.z, BFLO(u.w), a2); a3 = fmaf(Wb.w, BFHI(u.w), a3); }

    float xa;
    XDOT(xa, 0)

    const unsigned short* hrd = hs16[0];
    unsigned short*       hwr = hs16[1];

#pragma unroll 1
    for (int s = 0; s < T_STEPS - 1; ++s) {
        // ---- 4 b128 h reads issued first (DS pipe is in-order) ----
        const uint4* hp = (const uint4*)(hrd + 32 * q);
        const uint4 u0 = hp[0], u1 = hp[1], u2 = hp[2], u3 = hp[3];

        // next step's x-dot (1 b128), hidden under h-read latency
        float xa_next;
        XDOT(xa_next, s + 1)

        float a0 = xa, a1 = 0.f, a2 = 0.f, a3 = 0.f;
        HFMA8(u0, W0, W1) HFMA8(u1, W2, W3) HFMA8(u2, W4, W5) HFMA8(u3, W6, W7)
        float zp = (a0 + a1) + (a2 + a3);
        zp += __shfl_xor(zp, 1, 64);          // quad all-reduce over k-slices
        zp += __shfl_xor(zp, 2, 64);
        // branchless tanh: 1 - 2/(e^{2z}+1)
        const float e = __expf(2.0f * zp);
        const float h = 1.0f - 2.0f * __builtin_amdgcn_rcpf(e + 1.0f);
        if (q == 0) {                          // bf16 RNE store
            union { float f; uint32_t u; } cv; cv.f = h;
            const uint32_t r = cv.u + 0x7FFFu + ((cv.u >> 16) & 1u);
            hwr[row] = (unsigned short)(r >> 16);
        }
        __syncthreads();
        xa = xa_next;
        unsigned short* tmp = (unsigned short*)hrd; hrd = hwr; hwr = tmp;
    }
    {   // peeled final step: h written as f32 for the output head
        const uint4* hp = (const uint4*)(hrd + 32 * q);
        const uint4 u0 = hp[0], u1 = hp[1], u2 = hp[2], u3 = hp[3];
        float a0 = xa, a1 = 0.f, a2 = 0.f, a3 = 0.f;
        HFMA8(u0, W0, W1) HFMA8(u1, W2, W3) HFMA8(u2, W4, W5) HFMA8(u3, W6, W7)
        float zp = (a0 + a1) + (a2 + a3);
        zp += __shfl_xor(zp, 1, 64);
        zp += __shfl_xor(zp, 2, 64);
        const float e = __expf(2.0f * zp);
        const float h = 1.0f - 2.0f * __builtin_amdgcn_rcpf(e + 1.0f);
        if (q == 0) hf32[row] = h;
    }
    __syncthreads();

#undef XDOT
#undef HFMA8
#undef BFLO
#undef BFHI

    // ---- fused output head: out[b] = h @ W_out.T + b_out (f32 path) ----
    if (t < 10) {
        const float4* wo4 = (const float4*)(W_out + t * HIDDEN);
        const float4* h4  = (const float4*)hf32;
        float a0 = 0.f, a1 = 0.f, a2 = 0.f, a3 = 0.f;
#pragma unroll
        for (int k = 0; k < HIDDEN / 4; ++k) {
            const float4 w  = wo4[k];
            const float4 hv = h4[k];
            a0 = fmaf(w.x, hv.x, a0);
            a1 = fmaf(w.y, hv.y, a1);
            a2 = fmaf(w.z, hv.z, a2);
            a3 = fmaf(w.w, hv.w, a3);
        }
        out[b * 10 + t] = (a0 + a1) + (a2 + a3) + b_out[t];
    }
}

extern "C" void kernel_launch(void* const* d_in, const int* in_sizes, int n_in,
                              void* d_out, int out_size, void* d_ws, size_t ws_size,
                              hipStream_t stream) {
    const float* x     = (const float*)d_in[0];
    const float* W_in  = (const float*)d_in[1];
    const float* W_res = (const float*)d_in[2];
    const float* W_out = (const float*)d_in[3];
    const float* b_out = (const float*)d_in[4];
    float* out = (float*)d_out;

    esn_kernel<<<256, 512, 0, stream>>>(x, W_in, W_res, W_out, b_out, out);
}